// Round 1
// baseline (665.672 us; speedup 1.0000x reference)
//
#include <hip/hip_runtime.h>
#include <hip/hip_bf16.h>
#include <stdint.h>

#define B_DIM 32
#define T_DIM 2048
#define H_DIM 1024
#define M_DIM (B_DIM * T_DIM)   // 65536
#define K_DIM H_DIM              // 1024
#define N_DIM H_DIM              // 1024
#define BK 32

typedef __attribute__((ext_vector_type(4))) float f32x4;
typedef __attribute__((ext_vector_type(8))) short short8;

__device__ __forceinline__ unsigned short f2bf(float x) {
  // round-to-nearest-even fp32 -> bf16
  unsigned u = __float_as_uint(x);
  unsigned r = (u + 0x7FFFu + ((u >> 16) & 1u)) >> 16;
  return (unsigned short)r;
}

__device__ __forceinline__ float fast_tanh(float x) {
  x = fminf(fmaxf(x, -15.f), 15.f);
  float e = __expf(2.f * x);
  return (e - 1.f) / (e + 1.f);
}

// ---------------- convert G (fp32 -> bf16), 8 elems/thread ----------------
__global__ void convert_g_kernel(const float* __restrict__ in,
                                 unsigned short* __restrict__ out) {
  size_t base = ((size_t)blockIdx.x * 256 + threadIdx.x) * 8;
  const float4* p = (const float4*)(in + base);
  float4 u0 = p[0];
  float4 u1 = p[1];
  short8 s;
  s[0] = (short)f2bf(u0.x); s[1] = (short)f2bf(u0.y);
  s[2] = (short)f2bf(u0.z); s[3] = (short)f2bf(u0.w);
  s[4] = (short)f2bf(u1.x); s[5] = (short)f2bf(u1.y);
  s[6] = (short)f2bf(u1.z); s[7] = (short)f2bf(u1.w);
  *(short8*)(out + base) = s;
}

// ------------- convert + transpose W: Wt[n][k] = bf16(W[k][n]) -------------
__global__ void convert_w_kernel(const float* __restrict__ w,
                                 unsigned short* __restrict__ wt) {
  int g = blockIdx.x * 256 + threadIdx.x;   // 0 .. 1048575
  int n = g >> 10;
  int k = g & 1023;
  wt[g] = f2bf(w[k * 1024 + n]);
}

// ---- GEMM: logits[row] += sum_col c[col] * tanh( A[row,:] . Bt[col,:] ) ----
// A: [M][K] bf16 row-major, Bt: [N][K] bf16 row-major (= W transposed)
// 128x128 tile, BK=32, 4 waves (2x2 of 64x64), 16x16x32 bf16 MFMA,
// double-buffered LDS via global_load_lds (T3 minimal 2-phase recipe).
__global__ __launch_bounds__(256) void gemm_tanh_logits(
    const unsigned short* __restrict__ A,
    const unsigned short* __restrict__ Bt,
    const float* __restrict__ cvec,
    float* __restrict__ logits) {
  __shared__ unsigned short sA[2][128 * BK];
  __shared__ unsigned short sB[2][128 * BK];

  const int tid = threadIdx.x;
  const int wid = tid >> 6;
  const int lane = tid & 63;

  // XCD-aware swizzle: 4096 blocks, 8 XCDs -> contiguous 512-block chunks.
  int p = blockIdx.x;
  int logical = (p & 7) * 512 + (p >> 3);
  int mrow = logical >> 3;   // 0..511
  int ncol = logical & 7;    // 0..7

  const unsigned short* Abase = A + (size_t)mrow * 128 * K_DIM;
  const unsigned short* Bbase = Bt + (size_t)ncol * 128 * K_DIM;

  // each wave stages 32 rows of A-tile and 32 rows of B-tile
  auto stage = [&](int buf, int kt) {
    const int r0 = wid * 32;
#pragma unroll
    for (int q = 0; q < 2; ++q) {
      int row = r0 + q * 16 + (lane >> 2);
      int gcol = kt * BK + (lane & 3) * 8;
      const unsigned short* ga = Abase + (size_t)row * K_DIM + gcol;
      const unsigned short* gb = Bbase + (size_t)row * K_DIM + gcol;
      unsigned short* la = &sA[buf][(r0 + q * 16) * BK];  // wave-uniform dest
      unsigned short* lb = &sB[buf][(r0 + q * 16) * BK];
      __builtin_amdgcn_global_load_lds(
          (const __attribute__((address_space(1))) unsigned int*)ga,
          (__attribute__((address_space(3))) unsigned int*)la, 16, 0, 0);
      __builtin_amdgcn_global_load_lds(
          (const __attribute__((address_space(1))) unsigned int*)gb,
          (__attribute__((address_space(3))) unsigned int*)lb, 16, 0, 0);
    }
  };

  f32x4 acc[4][4];
#pragma unroll
  for (int m = 0; m < 4; ++m)
#pragma unroll
    for (int n = 0; n < 4; ++n)
      acc[m][n] = (f32x4){0.f, 0.f, 0.f, 0.f};

  stage(0, 0);
  asm volatile("s_waitcnt vmcnt(0)" ::: "memory");
  __syncthreads();

  const int wr = (wid >> 1) * 64;   // wave row offset in tile
  const int wc = (wid & 1) * 64;    // wave col offset in tile
  const int frow = lane & 15;
  const int fk = (lane >> 4) * 8;

  int cur = 0;
  for (int kt = 0; kt < K_DIM / BK; ++kt) {
    if (kt + 1 < K_DIM / BK) stage(cur ^ 1, kt + 1);
    short8 a[4], b[4];
#pragma unroll
    for (int m = 0; m < 4; ++m)
      a[m] = *(const short8*)&sA[cur][(wr + m * 16 + frow) * BK + fk];
#pragma unroll
    for (int n = 0; n < 4; ++n)
      b[n] = *(const short8*)&sB[cur][(wc + n * 16 + frow) * BK + fk];
#pragma unroll
    for (int m = 0; m < 4; ++m)
#pragma unroll
      for (int n = 0; n < 4; ++n)
        acc[m][n] = __builtin_amdgcn_mfma_f32_16x16x32_bf16(a[m], b[n],
                                                            acc[m][n], 0, 0, 0);
    asm volatile("s_waitcnt vmcnt(0)" ::: "memory");
    __syncthreads();
    cur ^= 1;
  }

  // epilogue: s[row] = sum over this tile's 64 cols of c[col]*tanh(acc)
  // C/D layout: col = lane&15, row = (lane>>4)*4 + j   [m89/m91 verified]
  const int cgrp = lane >> 4;
  const int cidx = lane & 15;
  const int colb = ncol * 128 + wc;
  const int rowb = mrow * 128 + wr;
#pragma unroll
  for (int m = 0; m < 4; ++m) {
    float s0 = 0.f, s1 = 0.f, s2 = 0.f, s3 = 0.f;
#pragma unroll
    for (int n = 0; n < 4; ++n) {
      float cw = cvec[colb + n * 16 + cidx];
      s0 += fast_tanh(acc[m][n][0]) * cw;
      s1 += fast_tanh(acc[m][n][1]) * cw;
      s2 += fast_tanh(acc[m][n][2]) * cw;
      s3 += fast_tanh(acc[m][n][3]) * cw;
    }
#pragma unroll
    for (int mask = 1; mask < 16; mask <<= 1) {
      s0 += __shfl_xor(s0, mask);
      s1 += __shfl_xor(s1, mask);
      s2 += __shfl_xor(s2, mask);
      s3 += __shfl_xor(s3, mask);
    }
    if (cidx == 0) {
      int row = rowb + m * 16 + cgrp * 4;
      atomicAdd(&logits[row + 0], s0);
      atomicAdd(&logits[row + 1], s1);
      atomicAdd(&logits[row + 2], s2);
      atomicAdd(&logits[row + 3], s3);
    }
  }
}

// -------- softmax over T (2048) per batch row, in-place on logits ----------
__global__ void softmax_kernel(float* __restrict__ la) {
  int b = blockIdx.x;
  float* row = la + (size_t)b * T_DIM;
  int tid = threadIdx.x;
  int wid = tid >> 6, lane = tid & 63;
  __shared__ float red[4];

  float v[8];
  float mx = -3.4e38f;
#pragma unroll
  for (int i = 0; i < 8; ++i) {
    v[i] = row[tid + i * 256];
    mx = fmaxf(mx, v[i]);
  }
#pragma unroll
  for (int mask = 32; mask >= 1; mask >>= 1) mx = fmaxf(mx, __shfl_xor(mx, mask));
  if (lane == 0) red[wid] = mx;
  __syncthreads();
  mx = fmaxf(fmaxf(red[0], red[1]), fmaxf(red[2], red[3]));
  __syncthreads();

  float sum = 0.f;
#pragma unroll
  for (int i = 0; i < 8; ++i) {
    v[i] = __expf(v[i] - mx);
    sum += v[i];
  }
#pragma unroll
  for (int mask = 32; mask >= 1; mask >>= 1) sum += __shfl_xor(sum, mask);
  if (lane == 0) red[wid] = sum;
  __syncthreads();
  sum = red[0] + red[1] + red[2] + red[3];
  float inv = 1.f / sum;
#pragma unroll
  for (int i = 0; i < 8; ++i) row[tid + i * 256] = v[i] * inv;
}

// ------------- context[b][h] = sum_t attn[b][t] * G[b][t][h] --------------
// grid (4 h-chunks, 8 t-chunks, 32 b); fp32 atomics into zeroed d_out.
__global__ void context_kernel(const float* __restrict__ G,
                               const float* __restrict__ attn,
                               float* __restrict__ ctx) {
  int hc = blockIdx.x;
  int tc = blockIdx.y;
  int b = blockIdx.z;
  int h = hc * 256 + threadIdx.x;
  const float* g = G + (size_t)b * T_DIM * H_DIM + (size_t)tc * 256 * H_DIM + h;
  const float* a = attn + (size_t)b * T_DIM + tc * 256;
  float acc = 0.f;
#pragma unroll 4
  for (int t = 0; t < 256; ++t) acc += a[t] * g[(size_t)t * H_DIM];
  atomicAdd(&ctx[b * H_DIM + h], acc);
}

extern "C" void kernel_launch(void* const* d_in, const int* in_sizes, int n_in,
                              void* d_out, int out_size, void* d_ws, size_t ws_size,
                              hipStream_t stream) {
  const float* G = (const float*)d_in[0];   // [32][2048][1024]
  const float* W = (const float*)d_in[1];   // [1024][1024]
  const float* c = (const float*)d_in[2];   // [1024]
  float* out = (float*)d_out;
  float* ctx = out;                          // [32][1024]
  float* attn = out + B_DIM * H_DIM;         // [32][2048] (logits, then attn)

  unsigned short* Gb = (unsigned short*)d_ws;                       // 128 MB
  unsigned short* Wt = (unsigned short*)((char*)d_ws +
                                         (size_t)M_DIM * K_DIM * 2); // 2 MB

  // zero logits + context accumulators (harness poisons d_out with 0xAA)
  hipMemsetAsync(d_out, 0, (size_t)out_size * sizeof(float), stream);

  convert_g_kernel<<<M_DIM * K_DIM / (256 * 8), 256, 0, stream>>>(G, Gb);
  convert_w_kernel<<<N_DIM * K_DIM / 256, 256, 0, stream>>>(W, Wt);
  gemm_tanh_logits<<<(M_DIM / 128) * (N_DIM / 128), 256, 0, stream>>>(Gb, Wt, c, attn);
  softmax_kernel<<<B_DIM, 256, 0, stream>>>(attn);
  context_kernel<<<dim3(4, 8, 32), 256, 0, stream>>>(G, attn, ctx);
}

// Round 3
// 571.649 us; speedup vs baseline: 1.1645x; 1.1645x over previous
//
#include <hip/hip_runtime.h>
#include <hip/hip_bf16.h>
#include <stdint.h>

#define B_DIM 32
#define T_DIM 2048
#define H_DIM 1024
#define M_DIM (B_DIM * T_DIM)   // 65536
#define K_DIM H_DIM              // 1024
#define N_DIM H_DIM              // 1024

// GEMM geometry
#define BM 256
#define BN 256
#define BKT 32
#define NTILES (K_DIM / BKT)     // 32
#define DEPTH 3                  // tiles prefetched ahead (4 LDS buffers)

typedef __attribute__((ext_vector_type(4))) float f32x4;
typedef __attribute__((ext_vector_type(8))) short short8;
typedef __attribute__((ext_vector_type(4))) short short4v;

__device__ __forceinline__ unsigned short f2bf(float x) {
  unsigned u = __float_as_uint(x);
  return (unsigned short)((u + 0x7FFFu + ((u >> 16) & 1u)) >> 16);
}
__device__ __forceinline__ float bf2f(unsigned short h) {
  return __uint_as_float(((unsigned)h) << 16);
}
__device__ __forceinline__ float fast_tanh(float x) {
  float e = __expf(2.f * x);
  return 1.f - 2.f / (e + 1.f);
}
// Swizzled byte offset of 16B slot s (0..3) of row r in a [256][32]bf16 tile.
// Pair-interleaved rows (128B unit = 8 slots), slot XOR'd with row-pair bits:
// per 16-lane frag-read group every 16B bank-slot is hit exactly 2x -> free.
__device__ __forceinline__ int swz(int r, int s) {
  return ((r >> 1) << 7) + (((((r & 1) << 2) | s) ^ ((r >> 1) & 7)) << 4);
}

// ---------------- convert G (fp32 -> bf16), grid-stride ----------------
__global__ void convert_g_kernel(const float* __restrict__ in,
                                 unsigned short* __restrict__ out) {
  size_t nvec = (size_t)M_DIM * K_DIM / 8;
  size_t stride = (size_t)gridDim.x * blockDim.x;
  for (size_t i = (size_t)blockIdx.x * blockDim.x + threadIdx.x; i < nvec;
       i += stride) {
    const float4* p = (const float4*)(in + i * 8);
    float4 u0 = p[0], u1 = p[1];
    short8 s;
    s[0] = (short)f2bf(u0.x); s[1] = (short)f2bf(u0.y);
    s[2] = (short)f2bf(u0.z); s[3] = (short)f2bf(u0.w);
    s[4] = (short)f2bf(u1.x); s[5] = (short)f2bf(u1.y);
    s[6] = (short)f2bf(u1.z); s[7] = (short)f2bf(u1.w);
    *(short8*)(out + i * 8) = s;
  }
}

// ------- convert + transpose W via LDS: Wt[n][k] = bf16(W[k][n]) -------
__global__ void convert_w_kernel(const float* __restrict__ w,
                                 unsigned short* __restrict__ wt) {
  __shared__ float tile[64][65];
  int n0 = blockIdx.x * 64;
  int k0 = blockIdx.y * 64;
  int j = threadIdx.x & 63;
  int i0 = threadIdx.x >> 6;  // 0..3
#pragma unroll
  for (int ii = 0; ii < 16; ++ii) {
    int i = i0 * 16 + ii;
    tile[i][j] = w[(size_t)(k0 + i) * H_DIM + n0 + j];  // coalesced read
  }
  __syncthreads();
#pragma unroll
  for (int ii = 0; ii < 16; ++ii) {
    int i = i0 * 16 + ii;
    wt[(size_t)(n0 + i) * H_DIM + k0 + j] = f2bf(tile[j][i]);  // coalesced write
  }
}

// ---- GEMM: logits[row] += sum_col c[col] * tanh( A[row,:] . Bt[col,:] ) ----
// 256x256 tile, BK=32, 8 waves (2M x 4N), 4-deep circular LDS prefetch,
// counted vmcnt (T4), both-sides swizzle (T2), setprio around MFMA (T5).
__global__ __launch_bounds__(512, 2) void gemm_tanh_logits(
    const unsigned short* __restrict__ A,
    const unsigned short* __restrict__ Bt,
    const float* __restrict__ cvec,
    float* __restrict__ logits) {
  __shared__ unsigned short lds[4][BM * BKT + BN * BKT];  // 4 x 32KB = 128KB

  const int tid = threadIdx.x;
  const int wid = tid >> 6;
  const int lane = tid & 63;

  // XCD-aware swizzle: 1024 blocks, 8 XCDs, 128 contiguous logical per XCD.
  int p = blockIdx.x;
  int logical = (p & 7) * 128 + (p >> 3);
  int mrow = logical >> 2;  // 0..255
  int ncol = logical & 3;   // 0..3

  const unsigned short* Ap = A + (size_t)mrow * BM * K_DIM;
  const unsigned short* Bp = Bt + (size_t)ncol * BN * K_DIM;

  // stage one half-tile (h=0: A 16KB, h=1: B 16KB) of K-tile t.
  // LDS dest is linear (wave-uniform base + lane*16); the SOURCE address is
  // pre-swizzled so that swizzled reads see logical data (rule #21).
  auto stage_half = [&](int t, int h) {
    int buf = t & 3;
    const unsigned short* gp = h ? Bp : Ap;
    unsigned short* base = &lds[buf][h ? BM * BKT : 0];
#pragma unroll
    for (int j = 0; j < 2; ++j) {
      int o = j * 8192 + tid * 16;        // byte offset in the 16KB half
      int pr = o >> 7;                    // row pair
      int v = ((o >> 4) & 7) ^ (pr & 7);  // undo swizzle
      int r = (pr << 1) | (v >> 2);
      int s = v & 3;
      const unsigned short* ga = gp + (size_t)r * K_DIM + t * BKT + s * 8;
      unsigned short* la = base + ((j * 8192 + wid * 1024) >> 1);
      __builtin_amdgcn_global_load_lds(
          (const __attribute__((address_space(1))) unsigned int*)ga,
          (__attribute__((address_space(3))) unsigned int*)la, 16, 0, 0);
    }
  };

  const int wm = wid >> 2;  // 0..1 -> rows wm*128..+128
  const int wn = wid & 3;   // 0..3 -> cols wn*64..+64
  const int fr = lane & 15;
  const int sl = lane >> 4;

  // swz(r+16,s) = swz(r,s) + 1024B -> frag offsets are linear in frag index.
  const int aoff = swz(wm * 128 + fr, sl) >> 1;              // ushort units
  const int boff = (swz(wn * 64 + fr, sl) >> 1) + BM * BKT;  // +512 per frag

  f32x4 acc[8][4];
#pragma unroll
  for (int m = 0; m < 8; ++m)
#pragma unroll
    for (int n = 0; n < 4; ++n) acc[m][n] = (f32x4){0.f, 0.f, 0.f, 0.f};

  // prologue: stage tiles 0..2 (12 loads/thread), wait tile 0 (8 in flight)
  stage_half(0, 0); stage_half(0, 1);
  stage_half(1, 0); stage_half(1, 1);
  stage_half(2, 0); stage_half(2, 1);
  asm volatile("s_waitcnt vmcnt(8)" ::: "memory");
  __builtin_amdgcn_s_barrier();

  for (int t = 0; t < NTILES; ++t) {
    const unsigned short* L0 = &lds[t & 3][0];
    short8 a[4], b[4];
    asm volatile("" ::: "memory");
    // ---- P0: stage A-half of t+3; frags a[0..3] + all b; MFMA m0-3 x n0-3
    if (t + DEPTH < NTILES) stage_half(t + DEPTH, 0);
#pragma unroll
    for (int m = 0; m < 4; ++m) a[m] = *(const short8*)(L0 + aoff + m * 512);
#pragma unroll
    for (int n = 0; n < 4; ++n) b[n] = *(const short8*)(L0 + boff + n * 512);
    __builtin_amdgcn_s_setprio(1);
#pragma unroll
    for (int m = 0; m < 4; ++m)
#pragma unroll
      for (int n = 0; n < 4; ++n)
        acc[m][n] = __builtin_amdgcn_mfma_f32_16x16x32_bf16(a[m], b[n],
                                                            acc[m][n], 0, 0, 0);
    __builtin_amdgcn_s_setprio(0);
    asm volatile("" ::: "memory");
    __builtin_amdgcn_s_barrier();
    asm volatile("" ::: "memory");
    // ---- P1: stage B-half of t+3; frags a[4..7]; MFMA m4-7 x n0-3
    if (t + DEPTH < NTILES) stage_half(t + DEPTH, 1);
#pragma unroll
    for (int m = 0; m < 4; ++m)
      a[m] = *(const short8*)(L0 + aoff + (m + 4) * 512);
    __builtin_amdgcn_s_setprio(1);
#pragma unroll
    for (int m = 0; m < 4; ++m)
#pragma unroll
      for (int n = 0; n < 4; ++n)
        acc[m + 4][n] = __builtin_amdgcn_mfma_f32_16x16x32_bf16(
            a[m], b[n], acc[m + 4][n], 0, 0, 0);
    __builtin_amdgcn_s_setprio(0);
    asm volatile("" ::: "memory");
    // counted vmcnt: require tile t+1 landed; keep tiles t+2,t+3 in flight
    if (t < NTILES - DEPTH)
      asm volatile("s_waitcnt vmcnt(8)" ::: "memory");
    else if (t == NTILES - DEPTH)
      asm volatile("s_waitcnt vmcnt(4)" ::: "memory");
    else if (t == NTILES - 2)
      asm volatile("s_waitcnt vmcnt(0)" ::: "memory");
    __builtin_amdgcn_s_barrier();
  }

  // epilogue: logits[row] += sum_cols c[col]*tanh(acc)
  // C/D layout: col = lane&15, row = (lane>>4)*4 + j
  const int cgrp = lane >> 4;
  const int cidx = lane & 15;
  const int colb = ncol * BN + wn * 64;
  const int rowb = mrow * BM + wm * 128;
#pragma unroll
  for (int m = 0; m < 8; ++m) {
    float s0 = 0.f, s1 = 0.f, s2 = 0.f, s3 = 0.f;
#pragma unroll
    for (int n = 0; n < 4; ++n) {
      float cw = cvec[colb + n * 16 + cidx];
      s0 += fast_tanh(acc[m][n][0]) * cw;
      s1 += fast_tanh(acc[m][n][1]) * cw;
      s2 += fast_tanh(acc[m][n][2]) * cw;
      s3 += fast_tanh(acc[m][n][3]) * cw;
    }
#pragma unroll
    for (int mask = 1; mask < 16; mask <<= 1) {
      s0 += __shfl_xor(s0, mask);
      s1 += __shfl_xor(s1, mask);
      s2 += __shfl_xor(s2, mask);
      s3 += __shfl_xor(s3, mask);
    }
    if (cidx == 0) {
      int row = rowb + m * 16 + cgrp * 4;
      atomicAdd(&logits[row + 0], s0);
      atomicAdd(&logits[row + 1], s1);
      atomicAdd(&logits[row + 2], s2);
      atomicAdd(&logits[row + 3], s3);
    }
  }
}

// -------- softmax over T (2048) per batch row, in-place on logits ----------
__global__ void softmax_kernel(float* __restrict__ la) {
  int b = blockIdx.x;
  float* row = la + (size_t)b * T_DIM;
  int tid = threadIdx.x;
  int wid = tid >> 6, lane = tid & 63;
  __shared__ float red[4];

  float v[8];
  float mx = -3.4e38f;
#pragma unroll
  for (int i = 0; i < 8; ++i) {
    v[i] = row[tid + i * 256];
    mx = fmaxf(mx, v[i]);
  }
#pragma unroll
  for (int mask = 32; mask >= 1; mask >>= 1) mx = fmaxf(mx, __shfl_xor(mx, mask));
  if (lane == 0) red[wid] = mx;
  __syncthreads();
  mx = fmaxf(fmaxf(red[0], red[1]), fmaxf(red[2], red[3]));
  __syncthreads();

  float sum = 0.f;
#pragma unroll
  for (int i = 0; i < 8; ++i) {
    v[i] = __expf(v[i] - mx);
    sum += v[i];
  }
#pragma unroll
  for (int mask = 32; mask >= 1; mask >>= 1) sum += __shfl_xor(sum, mask);
  if (lane == 0) red[wid] = sum;
  __syncthreads();
  sum = red[0] + red[1] + red[2] + red[3];
  float inv = 1.f / sum;
#pragma unroll
  for (int i = 0; i < 8; ++i) row[tid + i * 256] = v[i] * inv;
}

// --- context[b][h] = sum_t attn[b][t]*G[b][t][h], reading bf16 G copy ---
__global__ void context_kernel(const unsigned short* __restrict__ Gb,
                               const float* __restrict__ attn,
                               float* __restrict__ ctx) {
  int tc = blockIdx.x;  // 0..15 (128 t each)
  int b = blockIdx.y;   // 0..31
  int h = threadIdx.x * 4;
  const unsigned short* g = Gb + ((size_t)b * T_DIM + tc * 128) * H_DIM + h;
  const float* a = attn + b * T_DIM + tc * 128;
  float s0 = 0.f, s1 = 0.f, s2 = 0.f, s3 = 0.f;
#pragma unroll 4
  for (int t = 0; t < 128; ++t) {
    short4v v = *(const short4v*)(g + (size_t)t * H_DIM);
    float w = a[t];
    s0 += w * bf2f((unsigned short)v[0]);
    s1 += w * bf2f((unsigned short)v[1]);
    s2 += w * bf2f((unsigned short)v[2]);
    s3 += w * bf2f((unsigned short)v[3]);
  }
  float* cb = ctx + b * H_DIM + h;
  atomicAdd(cb + 0, s0);
  atomicAdd(cb + 1, s1);
  atomicAdd(cb + 2, s2);
  atomicAdd(cb + 3, s3);
}

extern "C" void kernel_launch(void* const* d_in, const int* in_sizes, int n_in,
                              void* d_out, int out_size, void* d_ws, size_t ws_size,
                              hipStream_t stream) {
  const float* G = (const float*)d_in[0];  // [32][2048][1024]
  const float* W = (const float*)d_in[1];  // [1024][1024]
  const float* c = (const float*)d_in[2];  // [1024]
  float* out = (float*)d_out;
  float* ctx = out;                         // [32][1024]
  float* attn = out + B_DIM * H_DIM;        // [32][2048] logits -> attn

  unsigned short* Gb = (unsigned short*)d_ws;                        // 128MB
  unsigned short* Wt = (unsigned short*)((char*)d_ws +
                                         (size_t)M_DIM * K_DIM * 2);  // 2MB

  hipMemsetAsync(d_out, 0, (size_t)out_size * sizeof(float), stream);

  convert_g_kernel<<<4096, 256, 0, stream>>>(G, Gb);
  convert_w_kernel<<<dim3(16, 16), 256, 0, stream>>>(W, Wt);
  gemm_tanh_logits<<<1024, 512, 0, stream>>>(Gb, Wt, c, attn);
  softmax_kernel<<<B_DIM, 256, 0, stream>>>(attn);
  context_kernel<<<dim3(16, 32), 256, 0, stream>>>(Gb, attn, ctx);
}

// Round 6
// 565.806 us; speedup vs baseline: 1.1765x; 1.0103x over previous
//
#include <hip/hip_runtime.h>
#include <hip/hip_bf16.h>
#include <stdint.h>

#define B_DIM 32
#define T_DIM 2048
#define H_DIM 1024
#define M_DIM (B_DIM * T_DIM)   // 65536
#define K_DIM H_DIM              // 1024
#define N_DIM H_DIM              // 1024

// GEMM geometry
#define BM 256
#define BN 256
#define BKT 32
#define NTILES (K_DIM / BKT)     // 32
#define DEPTH 3                  // tiles prefetched ahead (4 LDS buffers)

typedef __attribute__((ext_vector_type(4))) float f32x4;
typedef __attribute__((ext_vector_type(8))) short short8;
typedef __attribute__((ext_vector_type(4))) short short4v;

__device__ __forceinline__ unsigned short f2bf(float x) {
  unsigned u = __float_as_uint(x);
  return (unsigned short)((u + 0x7FFFu + ((u >> 16) & 1u)) >> 16);
}
__device__ __forceinline__ float bf2f(unsigned short h) {
  return __uint_as_float(((unsigned)h) << 16);
}
__device__ __forceinline__ float fast_tanh(float x) {
  float e = __expf(2.f * x);
  return 1.f - 2.f / (e + 1.f);
}
// Swizzled byte offset of 16B slot s (0..3) of row r in a [256][32]bf16 tile.
// Pair-interleaved rows (128B unit = 8 slots), slot XOR'd with row-pair bits.
// Verified R3: SQ_LDS_BANK_CONFLICT == 0.
__device__ __forceinline__ int swz(int r, int s) {
  return ((r >> 1) << 7) + (((((r & 1) << 2) | s) ^ ((r >> 1) & 7)) << 4);
}

// ---------------- convert G (fp32 -> bf16), grid-stride ----------------
__global__ void convert_g_kernel(const float* __restrict__ in,
                                 unsigned short* __restrict__ out) {
  size_t nvec = (size_t)M_DIM * K_DIM / 8;
  size_t stride = (size_t)gridDim.x * blockDim.x;
  for (size_t i = (size_t)blockIdx.x * blockDim.x + threadIdx.x; i < nvec;
       i += stride) {
    const float4* p = (const float4*)(in + i * 8);
    float4 u0 = p[0], u1 = p[1];
    short8 s;
    s[0] = (short)f2bf(u0.x); s[1] = (short)f2bf(u0.y);
    s[2] = (short)f2bf(u0.z); s[3] = (short)f2bf(u0.w);
    s[4] = (short)f2bf(u1.x); s[5] = (short)f2bf(u1.y);
    s[6] = (short)f2bf(u1.z); s[7] = (short)f2bf(u1.w);
    *(short8*)(out + i * 8) = s;
  }
}

// ------- convert + transpose W via LDS: Wt[n][k] = bf16(W[k][n]) -------
__global__ void convert_w_kernel(const float* __restrict__ w,
                                 unsigned short* __restrict__ wt) {
  __shared__ float tile[64][65];
  int n0 = blockIdx.x * 64;
  int k0 = blockIdx.y * 64;
  int j = threadIdx.x & 63;
  int i0 = threadIdx.x >> 6;  // 0..3
#pragma unroll
  for (int ii = 0; ii < 16; ++ii) {
    int i = i0 * 16 + ii;
    tile[i][j] = w[(size_t)(k0 + i) * H_DIM + n0 + j];
  }
  __syncthreads();
#pragma unroll
  for (int ii = 0; ii < 16; ++ii) {
    int i = i0 * 16 + ii;
    wt[(size_t)(n0 + i) * H_DIM + k0 + j] = f2bf(tile[j][i]);
  }
}

// ---- GEMM: logits[row] += sum_col c[col] * tanh( A[row,:] . Bt[col,:] ) ----
// 256x256 tile, BK=32, 8 waves (2M x 4N), 4-deep circular LDS prefetch,
// counted vmcnt (T4), both-sides swizzle (T2), setprio (T5),
// m201-style two-barrier phases, hoisted addressing, unroll-4 static bufs.
__global__ __launch_bounds__(512, 2) void gemm_tanh_logits(
    const unsigned short* __restrict__ A,
    const unsigned short* __restrict__ Bt,
    const float* __restrict__ cvec,
    float* __restrict__ logits) {
  // 4 buffers x (A-half 8192 + B-half 8192) ushorts = 128 KB
  __shared__ unsigned short lds[4 * 16384];

  const int tid = threadIdx.x;
  const int wid = tid >> 6;
  const int lane = tid & 63;

  // XCD-aware swizzle: 1024 blocks, 8 XCDs, 128 contiguous logical per XCD.
  int p = blockIdx.x;
  int logical = (p & 7) * 128 + (p >> 3);
  int mrow = logical >> 2;  // 0..255
  int ncol = logical & 3;   // 0..3

  const unsigned short* Ap = A + (size_t)mrow * BM * K_DIM;
  const unsigned short* Bp = Bt + (size_t)ncol * BN * K_DIM;

  // Hoisted per-thread staging source pointers (swizzle pre-decoded once).
  const unsigned short *gA[2], *gB[2];
#pragma unroll
  for (int j = 0; j < 2; ++j) {
    int o = j * 8192 + tid * 16;        // byte offset within 16KB half
    int pr = o >> 7;                    // row pair
    int v = ((o >> 4) & 7) ^ (pr & 7);  // undo swizzle
    int r = (pr << 1) | (v >> 2);
    int s = v & 3;
    gA[j] = Ap + (size_t)r * K_DIM + s * 8;
    gB[j] = Bp + (size_t)r * K_DIM + s * 8;
  }
  const int ldst0 = wid * 512;           // ushort offset, j=0
  const int ldst1 = wid * 512 + 4096;    // ushort offset, j=1

  // stage A-half / B-half of K-tile tt into buffer bi (bi compile-time
  // after unroll). LDS dest linear; source pre-swizzled (rule #21).
  auto stageA = [&](int tt, int bi) {
    __builtin_amdgcn_global_load_lds(
        (const __attribute__((address_space(1))) unsigned int*)(gA[0] + tt * BKT),
        (__attribute__((address_space(3))) unsigned int*)(lds + bi * 16384 + ldst0),
        16, 0, 0);
    __builtin_amdgcn_global_load_lds(
        (const __attribute__((address_space(1))) unsigned int*)(gA[1] + tt * BKT),
        (__attribute__((address_space(3))) unsigned int*)(lds + bi * 16384 + ldst1),
        16, 0, 0);
  };
  auto stageB = [&](int tt, int bi) {
    __builtin_amdgcn_global_load_lds(
        (const __attribute__((address_space(1))) unsigned int*)(gB[0] + tt * BKT),
        (__attribute__((address_space(3))) unsigned int*)(lds + bi * 16384 + 8192 + ldst0),
        16, 0, 0);
    __builtin_amdgcn_global_load_lds(
        (const __attribute__((address_space(1))) unsigned int*)(gB[1] + tt * BKT),
        (__attribute__((address_space(3))) unsigned int*)(lds + bi * 16384 + 8192 + ldst1),
        16, 0, 0);
  };

  const int wm = wid >> 2;  // 0..1 -> rows wm*128..+128
  const int wn = wid & 3;   // 0..3 -> cols wn*64..+64
  const int fr = lane & 15;
  const int sl = lane >> 4;

  // swz(r+16,s) = swz(r,s) + 1024B -> frag offsets linear in frag index.
  const int aoff = swz(wm * 128 + fr, sl) >> 1;        // ushort units
  const int boff = (swz(wn * 64 + fr, sl) >> 1) + 8192;

  f32x4 acc[8][4];
#pragma unroll
  for (int m = 0; m < 8; ++m)
#pragma unroll
    for (int n = 0; n < 4; ++n) acc[m][n] = (f32x4){0.f, 0.f, 0.f, 0.f};

  // prologue: stage tiles 0..2 (12 loads/thread), wait tile 0 (8 in flight)
  stageA(0, 0); stageB(0, 0);
  stageA(1, 1); stageB(1, 1);
  stageA(2, 2); stageB(2, 2);
  asm volatile("s_waitcnt vmcnt(8)" ::: "memory");
  __builtin_amdgcn_s_barrier();

  for (int T = 0; T < NTILES; T += 4) {
#pragma unroll
    for (int u = 0; u < 4; ++u) {
      const int t = T + u;
      const unsigned short* L0 = lds + u * 16384;  // (t&3)==u, static
      short8 a[4], b[4], a2[4];
      // ================= PHASE A: frags a[0-3], b[0-3]; MFMA m0-3 =========
#pragma unroll
      for (int m = 0; m < 4; ++m) a[m] = *(const short8*)(L0 + aoff + m * 512);
#pragma unroll
      for (int n = 0; n < 4; ++n) b[n] = *(const short8*)(L0 + boff + n * 512);
      if (t + DEPTH < NTILES) stageA(t + DEPTH, (u + 3) & 3);
      __builtin_amdgcn_sched_barrier(0);
      __builtin_amdgcn_s_barrier();
      asm volatile("s_waitcnt lgkmcnt(0)" ::: "memory");
      __builtin_amdgcn_sched_barrier(0);
      __builtin_amdgcn_s_setprio(1);
#pragma unroll
      for (int m = 0; m < 4; ++m)
#pragma unroll
        for (int n = 0; n < 4; ++n)
          acc[m][n] = __builtin_amdgcn_mfma_f32_16x16x32_bf16(a[m], b[n],
                                                              acc[m][n], 0, 0, 0);
      __builtin_amdgcn_s_setprio(0);
      __builtin_amdgcn_sched_barrier(0);
      __builtin_amdgcn_s_barrier();
      // ================= PHASE B: frags a[4-7]; MFMA m4-7 =================
#pragma unroll
      for (int m = 0; m < 4; ++m)
        a2[m] = *(const short8*)(L0 + aoff + (m + 4) * 512);
      if (t + DEPTH < NTILES) stageB(t + DEPTH, (u + 3) & 3);
      __builtin_amdgcn_sched_barrier(0);
      __builtin_amdgcn_s_barrier();
      asm volatile("s_waitcnt lgkmcnt(0)" ::: "memory");
      __builtin_amdgcn_sched_barrier(0);
      __builtin_amdgcn_s_setprio(1);
#pragma unroll
      for (int m = 0; m < 4; ++m)
#pragma unroll
        for (int n = 0; n < 4; ++n)
          acc[m + 4][n] = __builtin_amdgcn_mfma_f32_16x16x32_bf16(
              a2[m], b[n], acc[m + 4][n], 0, 0, 0);
      __builtin_amdgcn_s_setprio(0);
      __builtin_amdgcn_sched_barrier(0);
      // counted vmcnt: tile t+1 must have landed; keep t+2,t+3 in flight
      if (t < NTILES - DEPTH)
        asm volatile("s_waitcnt vmcnt(8)" ::: "memory");
      else if (t == NTILES - DEPTH)
        asm volatile("s_waitcnt vmcnt(4)" ::: "memory");
      else if (t == NTILES - 2)
        asm volatile("s_waitcnt vmcnt(0)" ::: "memory");
      __builtin_amdgcn_s_barrier();
    }
  }

  // epilogue: logits[row] += sum_cols c[col]*tanh(acc)
  // C/D layout: col = lane&15, row = (lane>>4)*4 + j
  const int cgrp = lane >> 4;
  const int cidx = lane & 15;
  const int colb = ncol * BN + wn * 64;
  const int rowb = mrow * BM + wm * 128;
  float cw[4];
#pragma unroll
  for (int n = 0; n < 4; ++n) cw[n] = cvec[colb + n * 16 + cidx];
#pragma unroll
  for (int m = 0; m < 8; ++m) {
    float s0 = 0.f, s1 = 0.f, s2 = 0.f, s3 = 0.f;
#pragma unroll
    for (int n = 0; n < 4; ++n) {
      s0 += fast_tanh(acc[m][n][0]) * cw[n];
      s1 += fast_tanh(acc[m][n][1]) * cw[n];
      s2 += fast_tanh(acc[m][n][2]) * cw[n];
      s3 += fast_tanh(acc[m][n][3]) * cw[n];
    }
#pragma unroll
    for (int mask = 1; mask < 16; mask <<= 1) {
      s0 += __shfl_xor(s0, mask);
      s1 += __shfl_xor(s1, mask);
      s2 += __shfl_xor(s2, mask);
      s3 += __shfl_xor(s3, mask);
    }
    if (cidx == 0) {
      int row = rowb + m * 16 + cgrp * 4;
      atomicAdd(&logits[row + 0], s0);
      atomicAdd(&logits[row + 1], s1);
      atomicAdd(&logits[row + 2], s2);
      atomicAdd(&logits[row + 3], s3);
    }
  }
}

// -------- softmax over T (2048) per batch row, in-place on logits ----------
__global__ void softmax_kernel(float* __restrict__ la) {
  int b = blockIdx.x;
  float* row = la + (size_t)b * T_DIM;
  int tid = threadIdx.x;
  int wid = tid >> 6, lane = tid & 63;
  __shared__ float red[4];

  float v[8];
  float mx = -3.4e38f;
#pragma unroll
  for (int i = 0; i < 8; ++i) {
    v[i] = row[tid + i * 256];
    mx = fmaxf(mx, v[i]);
  }
#pragma unroll
  for (int mask = 32; mask >= 1; mask >>= 1) mx = fmaxf(mx, __shfl_xor(mx, mask));
  if (lane == 0) red[wid] = mx;
  __syncthreads();
  mx = fmaxf(fmaxf(red[0], red[1]), fmaxf(red[2], red[3]));
  __syncthreads();

  float sum = 0.f;
#pragma unroll
  for (int i = 0; i < 8; ++i) {
    v[i] = __expf(v[i] - mx);
    sum += v[i];
  }
#pragma unroll
  for (int mask = 32; mask >= 1; mask >>= 1) sum += __shfl_xor(sum, mask);
  if (lane == 0) red[wid] = sum;
  __syncthreads();
  sum = red[0] + red[1] + red[2] + red[3];
  float inv = 1.f / sum;
#pragma unroll
  for (int i = 0; i < 8; ++i) row[tid + i * 256] = v[i] * inv;
}

// --- context[b][h] = sum_t attn[b][t]*G[b][t][h], reading bf16 G copy ---
__global__ void context_kernel(const unsigned short* __restrict__ Gb,
                               const float* __restrict__ attn,
                               float* __restrict__ ctx) {
  int tc = blockIdx.x;  // 0..15 (128 t each)
  int b = blockIdx.y;   // 0..31
  int h = threadIdx.x * 4;
  const unsigned short* g = Gb + ((size_t)b * T_DIM + tc * 128) * H_DIM + h;
  const float* a = attn + b * T_DIM + tc * 128;
  float s0 = 0.f, s1 = 0.f, s2 = 0.f, s3 = 0.f;
#pragma unroll 4
  for (int t = 0; t < 128; ++t) {
    short4v v = *(const short4v*)(g + (size_t)t * H_DIM);
    float w = a[t];
    s0 += w * bf2f((unsigned short)v[0]);
    s1 += w * bf2f((unsigned short)v[1]);
    s2 += w * bf2f((unsigned short)v[2]);
    s3 += w * bf2f((unsigned short)v[3]);
  }
  float* cb = ctx + b * H_DIM + h;
  atomicAdd(cb + 0, s0);
  atomicAdd(cb + 1, s1);
  atomicAdd(cb + 2, s2);
  atomicAdd(cb + 3, s3);
}

extern "C" void kernel_launch(void* const* d_in, const int* in_sizes, int n_in,
                              void* d_out, int out_size, void* d_ws, size_t ws_size,
                              hipStream_t stream) {
  const float* G = (const float*)d_in[0];  // [32][2048][1024]
  const float* W = (const float*)d_in[1];  // [1024][1024]
  const float* c = (const float*)d_in[2];  // [1024]
  float* out = (float*)d_out;
  float* ctx = out;                         // [32][1024]
  float* attn = out + B_DIM * H_DIM;        // [32][2048] logits -> attn

  unsigned short* Gb = (unsigned short*)d_ws;                        // 128MB
  unsigned short* Wt = (unsigned short*)((char*)d_ws +
                                         (size_t)M_DIM * K_DIM * 2);  // 2MB

  hipMemsetAsync(d_out, 0, (size_t)out_size * sizeof(float), stream);

  convert_g_kernel<<<4096, 256, 0, stream>>>(G, Gb);
  convert_w_kernel<<<dim3(16, 16), 256, 0, stream>>>(W, Wt);
  gemm_tanh_logits<<<1024, 512, 0, stream>>>(Gb, Wt, c, attn);
  softmax_kernel<<<B_DIM, 256, 0, stream>>>(attn);
  context_kernel<<<dim3(16, 32), 256, 0, stream>>>(Gb, attn, ctx);
}

// Round 8
// 558.803 us; speedup vs baseline: 1.1912x; 1.0125x over previous
//
#include <hip/hip_runtime.h>
#include <hip/hip_bf16.h>
#include <stdint.h>

#define B_DIM 32
#define T_DIM 2048
#define H_DIM 1024
#define M_DIM (B_DIM * T_DIM)   // 65536
#define K_DIM H_DIM              // 1024
#define N_DIM H_DIM              // 1024

// GEMM geometry
#define BM 256
#define BN 256
#define BKT 32
#define NTILES (K_DIM / BKT)     // 32
#define DEPTH 3                  // tiles prefetched ahead (4 LDS buffers)

typedef __attribute__((ext_vector_type(4))) float f32x4;
typedef __attribute__((ext_vector_type(8))) short short8;
typedef __attribute__((ext_vector_type(4))) short short4v;

__device__ __forceinline__ unsigned short f2bf(float x) {
  unsigned u = __float_as_uint(x);
  return (unsigned short)((u + 0x7FFFu + ((u >> 16) & 1u)) >> 16);
}
__device__ __forceinline__ float bf2f(unsigned short h) {
  return __uint_as_float(((unsigned)h) << 16);
}
__device__ __forceinline__ float fast_tanh(float x) {
  float e = __expf(2.f * x);
  return 1.f - 2.f / (e + 1.f);
}
// Swizzled byte offset of 16B slot s (0..3) of row r in a [256][32]bf16 tile.
// Verified R3/R6: SQ_LDS_BANK_CONFLICT == 0.
__device__ __forceinline__ int swz(int r, int s) {
  return ((r >> 1) << 7) + (((((r & 1) << 2) | s) ^ ((r >> 1) & 7)) << 4);
}

// ---------------- convert G (fp32 -> bf16), grid-stride ----------------
__global__ void convert_g_kernel(const float* __restrict__ in,
                                 unsigned short* __restrict__ out) {
  size_t nvec = (size_t)M_DIM * K_DIM / 8;
  size_t stride = (size_t)gridDim.x * blockDim.x;
  for (size_t i = (size_t)blockIdx.x * blockDim.x + threadIdx.x; i < nvec;
       i += stride) {
    const float4* p = (const float4*)(in + i * 8);
    float4 u0 = p[0], u1 = p[1];
    short8 s;
    s[0] = (short)f2bf(u0.x); s[1] = (short)f2bf(u0.y);
    s[2] = (short)f2bf(u0.z); s[3] = (short)f2bf(u0.w);
    s[4] = (short)f2bf(u1.x); s[5] = (short)f2bf(u1.y);
    s[6] = (short)f2bf(u1.z); s[7] = (short)f2bf(u1.w);
    *(short8*)(out + i * 8) = s;
  }
}

// ------- convert + transpose W via LDS: Wt[n][k] = bf16(W[k][n]) -------
__global__ void convert_w_kernel(const float* __restrict__ w,
                                 unsigned short* __restrict__ wt) {
  __shared__ float tile[64][65];
  int n0 = blockIdx.x * 64;
  int k0 = blockIdx.y * 64;
  int j = threadIdx.x & 63;
  int i0 = threadIdx.x >> 6;  // 0..3
#pragma unroll
  for (int ii = 0; ii < 16; ++ii) {
    int i = i0 * 16 + ii;
    tile[i][j] = w[(size_t)(k0 + i) * H_DIM + n0 + j];
  }
  __syncthreads();
#pragma unroll
  for (int ii = 0; ii < 16; ++ii) {
    int i = i0 * 16 + ii;
    wt[(size_t)(n0 + i) * H_DIM + k0 + j] = f2bf(tile[j][i]);
  }
}

// ---- GEMM: logits[row] += sum_col c[col] * tanh( A[row,:] . Bt[col,:] ) ----
// 256x256 tile, BK=32, 8 waves (2M x 4N), 4-deep circular LDS prefetch,
// counted vmcnt (T4), both-sides swizzle (T2), setprio (T5).
// R7: ncol-per-XCD block remap -> B-slice (512KB) stays L2-resident per XCD,
// removing B's 512MB re-read traffic from the shared L3/HBM pool.
__global__ __launch_bounds__(512, 2) void gemm_tanh_logits(
    const unsigned short* __restrict__ A,
    const unsigned short* __restrict__ Bt,
    const float* __restrict__ cvec,
    float* __restrict__ logits) {
  // 4 buffers x (A-half 8192 + B-half 8192) ushorts = 128 KB
  __shared__ unsigned short lds[4 * 16384];

  const int tid = threadIdx.x;
  const int wid = tid >> 6;
  const int lane = tid & 63;

  // B-stationary XCD map: xcd = bid&7 owns ncol = xcd&3 exclusively.
  // mrow = (xcd>>2)*128 + bid>>3. Bijective: 8 xcd x 128 = 4 ncol x 256 mrow.
  // XCDs sharing an mrow range (0-3 / 4-7) progress in lockstep -> A L3-hits.
  int p = blockIdx.x;
  int xcd = p & 7;
  int ncol = xcd & 3;                  // 0..3
  int mrow = (xcd >> 2) * 128 + (p >> 3);  // 0..255

  const unsigned short* Ap = A + (size_t)mrow * BM * K_DIM;
  const unsigned short* Bp = Bt + (size_t)ncol * BN * K_DIM;

  // Hoisted per-thread staging source pointers (swizzle pre-decoded once).
  const unsigned short *gA[2], *gB[2];
#pragma unroll
  for (int j = 0; j < 2; ++j) {
    int o = j * 8192 + tid * 16;        // byte offset within 16KB half
    int pr = o >> 7;                    // row pair
    int v = ((o >> 4) & 7) ^ (pr & 7);  // undo swizzle
    int r = (pr << 1) | (v >> 2);
    int s = v & 3;
    gA[j] = Ap + (size_t)r * K_DIM + s * 8;
    gB[j] = Bp + (size_t)r * K_DIM + s * 8;
  }
  const int ldst0 = wid * 512;           // ushort offset, j=0
  const int ldst1 = wid * 512 + 4096;    // ushort offset, j=1

  // stage A-half / B-half of K-tile tt into buffer bi (bi compile-time
  // after unroll). LDS dest linear; source pre-swizzled (rule #21).
  auto stageA = [&](int tt, int bi) {
    __builtin_amdgcn_global_load_lds(
        (const __attribute__((address_space(1))) unsigned int*)(gA[0] + tt * BKT),
        (__attribute__((address_space(3))) unsigned int*)(lds + bi * 16384 + ldst0),
        16, 0, 0);
    __builtin_amdgcn_global_load_lds(
        (const __attribute__((address_space(1))) unsigned int*)(gA[1] + tt * BKT),
        (__attribute__((address_space(3))) unsigned int*)(lds + bi * 16384 + ldst1),
        16, 0, 0);
  };
  auto stageB = [&](int tt, int bi) {
    __builtin_amdgcn_global_load_lds(
        (const __attribute__((address_space(1))) unsigned int*)(gB[0] + tt * BKT),
        (__attribute__((address_space(3))) unsigned int*)(lds + bi * 16384 + 8192 + ldst0),
        16, 0, 0);
    __builtin_amdgcn_global_load_lds(
        (const __attribute__((address_space(1))) unsigned int*)(gB[1] + tt * BKT),
        (__attribute__((address_space(3))) unsigned int*)(lds + bi * 16384 + 8192 + ldst1),
        16, 0, 0);
  };

  const int wm = wid >> 2;  // 0..1 -> rows wm*128..+128
  const int wn = wid & 3;   // 0..3 -> cols wn*64..+64
  const int fr = lane & 15;
  const int sl = lane >> 4;

  // swz(r+16,s) = swz(r,s) + 1024B -> frag offsets linear in frag index.
  const int aoff = swz(wm * 128 + fr, sl) >> 1;        // ushort units
  const int boff = (swz(wn * 64 + fr, sl) >> 1) + 8192;

  f32x4 acc[8][4];
#pragma unroll
  for (int m = 0; m < 8; ++m)
#pragma unroll
    for (int n = 0; n < 4; ++n) acc[m][n] = (f32x4){0.f, 0.f, 0.f, 0.f};

  // prologue: stage tiles 0..2 (12 loads/thread), wait tile 0 (8 in flight)
  stageA(0, 0); stageB(0, 0);
  stageA(1, 1); stageB(1, 1);
  stageA(2, 2); stageB(2, 2);
  asm volatile("s_waitcnt vmcnt(8)" ::: "memory");
  __builtin_amdgcn_s_barrier();

  for (int T = 0; T < NTILES; T += 4) {
#pragma unroll
    for (int u = 0; u < 4; ++u) {
      const int t = T + u;
      const unsigned short* L0 = lds + u * 16384;  // (t&3)==u, static
      short8 a[4], b[4], a2[4];
      // ================= PHASE A: frags a[0-3], b[0-3]; MFMA m0-3 =========
#pragma unroll
      for (int m = 0; m < 4; ++m) a[m] = *(const short8*)(L0 + aoff + m * 512);
#pragma unroll
      for (int n = 0; n < 4; ++n) b[n] = *(const short8*)(L0 + boff + n * 512);
      if (t + DEPTH < NTILES) stageA(t + DEPTH, (u + 3) & 3);
      __builtin_amdgcn_sched_barrier(0);
      __builtin_amdgcn_s_barrier();
      asm volatile("s_waitcnt lgkmcnt(0)" ::: "memory");
      __builtin_amdgcn_sched_barrier(0);
      __builtin_amdgcn_s_setprio(1);
#pragma unroll
      for (int m = 0; m < 4; ++m)
#pragma unroll
        for (int n = 0; n < 4; ++n)
          acc[m][n] = __builtin_amdgcn_mfma_f32_16x16x32_bf16(a[m], b[n],
                                                              acc[m][n], 0, 0, 0);
      __builtin_amdgcn_s_setprio(0);
      __builtin_amdgcn_sched_barrier(0);
      __builtin_amdgcn_s_barrier();
      // ================= PHASE B: frags a[4-7]; MFMA m4-7 =================
#pragma unroll
      for (int m = 0; m < 4; ++m)
        a2[m] = *(const short8*)(L0 + aoff + (m + 4) * 512);
      if (t + DEPTH < NTILES) stageB(t + DEPTH, (u + 3) & 3);
      __builtin_amdgcn_sched_barrier(0);
      __builtin_amdgcn_s_barrier();
      asm volatile("s_waitcnt lgkmcnt(0)" ::: "memory");
      __builtin_amdgcn_sched_barrier(0);
      __builtin_amdgcn_s_setprio(1);
#pragma unroll
      for (int m = 0; m < 4; ++m)
#pragma unroll
        for (int n = 0; n < 4; ++n)
          acc[m + 4][n] = __builtin_amdgcn_mfma_f32_16x16x32_bf16(
              a2[m], b[n], acc[m + 4][n], 0, 0, 0);
      __builtin_amdgcn_s_setprio(0);
      __builtin_amdgcn_sched_barrier(0);
      // counted vmcnt: tile t+1 must have landed; keep t+2,t+3 in flight
      if (t < NTILES - DEPTH)
        asm volatile("s_waitcnt vmcnt(8)" ::: "memory");
      else if (t == NTILES - DEPTH)
        asm volatile("s_waitcnt vmcnt(4)" ::: "memory");
      else if (t == NTILES - 2)
        asm volatile("s_waitcnt vmcnt(0)" ::: "memory");
      __builtin_amdgcn_s_barrier();
    }
  }

  // epilogue: logits[row] += sum_cols c[col]*tanh(acc)
  // C/D layout: col = lane&15, row = (lane>>4)*4 + j
  const int cgrp = lane >> 4;
  const int cidx = lane & 15;
  const int colb = ncol * BN + wn * 64;
  const int rowb = mrow * BM + wm * 128;
  float cw[4];
#pragma unroll
  for (int n = 0; n < 4; ++n) cw[n] = cvec[colb + n * 16 + cidx];
#pragma unroll
  for (int m = 0; m < 8; ++m) {
    float s0 = 0.f, s1 = 0.f, s2 = 0.f, s3 = 0.f;
#pragma unroll
    for (int n = 0; n < 4; ++n) {
      s0 += fast_tanh(acc[m][n][0]) * cw[n];
      s1 += fast_tanh(acc[m][n][1]) * cw[n];
      s2 += fast_tanh(acc[m][n][2]) * cw[n];
      s3 += fast_tanh(acc[m][n][3]) * cw[n];
    }
#pragma unroll
    for (int mask = 1; mask < 16; mask <<= 1) {
      s0 += __shfl_xor(s0, mask);
      s1 += __shfl_xor(s1, mask);
      s2 += __shfl_xor(s2, mask);
      s3 += __shfl_xor(s3, mask);
    }
    if (cidx == 0) {
      int row = rowb + m * 16 + cgrp * 4;
      atomicAdd(&logits[row + 0], s0);
      atomicAdd(&logits[row + 1], s1);
      atomicAdd(&logits[row + 2], s2);
      atomicAdd(&logits[row + 3], s3);
    }
  }
}

// -------- softmax over T (2048) per batch row, in-place on logits ----------
__global__ void softmax_kernel(float* __restrict__ la) {
  int b = blockIdx.x;
  float* row = la + (size_t)b * T_DIM;
  int tid = threadIdx.x;
  int wid = tid >> 6, lane = tid & 63;
  __shared__ float red[4];

  float v[8];
  float mx = -3.4e38f;
#pragma unroll
  for (int i = 0; i < 8; ++i) {
    v[i] = row[tid + i * 256];
    mx = fmaxf(mx, v[i]);
  }
#pragma unroll
  for (int mask = 32; mask >= 1; mask >>= 1) mx = fmaxf(mx, __shfl_xor(mx, mask));
  if (lane == 0) red[wid] = mx;
  __syncthreads();
  mx = fmaxf(fmaxf(red[0], red[1]), fmaxf(red[2], red[3]));
  __syncthreads();

  float sum = 0.f;
#pragma unroll
  for (int i = 0; i < 8; ++i) {
    v[i] = __expf(v[i] - mx);
    sum += v[i];
  }
#pragma unroll
  for (int mask = 32; mask >= 1; mask >>= 1) sum += __shfl_xor(sum, mask);
  if (lane == 0) red[wid] = sum;
  __syncthreads();
  sum = red[0] + red[1] + red[2] + red[3];
  float inv = 1.f / sum;
#pragma unroll
  for (int i = 0; i < 8; ++i) row[tid + i * 256] = v[i] * inv;
}

// --- context[b][h] = sum_t attn[b][t]*G[b][t][h], reading bf16 G copy ---
__global__ void context_kernel(const unsigned short* __restrict__ Gb,
                               const float* __restrict__ attn,
                               float* __restrict__ ctx) {
  int tc = blockIdx.x;  // 0..15 (128 t each)
  int b = blockIdx.y;   // 0..31
  int h = threadIdx.x * 4;
  const unsigned short* g = Gb + ((size_t)b * T_DIM + tc * 128) * H_DIM + h;
  const float* a = attn + b * T_DIM + tc * 128;
  float s0 = 0.f, s1 = 0.f, s2 = 0.f, s3 = 0.f;
#pragma unroll 4
  for (int t = 0; t < 128; ++t) {
    short4v v = *(const short4v*)(g + (size_t)t * H_DIM);
    float w = a[t];
    s0 += w * bf2f((unsigned short)v[0]);
    s1 += w * bf2f((unsigned short)v[1]);
    s2 += w * bf2f((unsigned short)v[2]);
    s3 += w * bf2f((unsigned short)v[3]);
  }
  float* cb = ctx + b * H_DIM + h;
  atomicAdd(cb + 0, s0);
  atomicAdd(cb + 1, s1);
  atomicAdd(cb + 2, s2);
  atomicAdd(cb + 3, s3);
}

extern "C" void kernel_launch(void* const* d_in, const int* in_sizes, int n_in,
                              void* d_out, int out_size, void* d_ws, size_t ws_size,
                              hipStream_t stream) {
  const float* G = (const float*)d_in[0];  // [32][2048][1024]
  const float* W = (const float*)d_in[1];  // [1024][1024]
  const float* c = (const float*)d_in[2];  // [1024]
  float* out = (float*)d_out;
  float* ctx = out;                         // [32][1024]
  float* attn = out + B_DIM * H_DIM;        // [32][2048] logits -> attn

  unsigned short* Gb = (unsigned short*)d_ws;                        // 128MB
  unsigned short* Wt = (unsigned short*)((char*)d_ws +
                                         (size_t)M_DIM * K_DIM * 2);  // 2MB

  hipMemsetAsync(d_out, 0, (size_t)out_size * sizeof(float), stream);

  convert_g_kernel<<<4096, 256, 0, stream>>>(G, Gb);
  convert_w_kernel<<<dim3(16, 16), 256, 0, stream>>>(W, Wt);
  gemm_tanh_logits<<<1024, 512, 0, stream>>>(Gb, Wt, c, attn);
  softmax_kernel<<<B_DIM, 256, 0, stream>>>(attn);
  context_kernel<<<dim3(16, 32), 256, 0, stream>>>(Gb, attn, ctx);
}